// Round 5
// baseline (3946.994 us; speedup 1.0000x reference)
//
#include <hip/hip_runtime.h>
#include <stdint.h>

typedef unsigned short u16;
typedef unsigned long long u64;
typedef short s8v __attribute__((ext_vector_type(8)));
typedef float f32x4 __attribute__((ext_vector_type(4)));

#define BT    64
#define TT    512
#define NINP  300
#define KX    320
#define HH    512
#define DAP   384
#define RR    30
#define RP    128
#define MROWS 32768
#define MLPH  2000
#define H2    1024
#define KSPL  8
#define KMLP  30720
#define KCH   (KMLP/KSPL)   // 3840

__device__ inline float b2f(u16 u){ union{unsigned i; float f;} v; v.i = ((unsigned)u)<<16; return v.f; }
__device__ inline u16 f2b(float x){ union{unsigned i; float f;} v; v.f = x; unsigned b = v.i;
  unsigned r = (b + 0x7fffu + ((b>>16)&1u))>>16; return (u16)r; }

// fast tanh: 1 - 2/(e^{2x}+1). Exact at +-inf, ~1e-6 rel err; bf16-safe.
__device__ inline float ftanh(float x){
  float e = __expf(2.f*x);
  return 1.f - 2.f/(e + 1.f);
}

// truncating f32x8 -> bf16x8 pack (streaming Wm)
__device__ inline s8v cvt8t(const float* p){
  union { unsigned u[4]; s8v v; } r;
  #pragma unroll
  for (int i=0;i<4;i++){
    unsigned lo = __float_as_uint(p[2*i])   >> 16;
    unsigned hi = __float_as_uint(p[2*i+1]) & 0xFFFF0000u;
    r.u[i] = lo | hi;
  }
  return r.v;
}

// ---------------- embedding gather f32->bf16 (+mask), t-major rows r = t*64+b ----------------
__global__ __launch_bounds__(256)
void embed_kernel(const int* __restrict__ ids, const int* __restrict__ lens,
                  const float* __restrict__ emb, u16* __restrict__ Xf)
{
  int w = blockIdx.x*4 + (threadIdx.x>>6);  // row 0..32767
  int lane = threadIdx.x & 63;
  int b = w & 63, t = w >> 6;
  int len = lens[b];
  int id = ids[b*TT + t];
  bool valid = t < len;
  const float* src = emb + (size_t)id*NINP;
  #pragma unroll
  for (int i=0;i<5;i++){
    int col = lane + i*64;
    float v = (valid && col < NINP) ? src[col] : 0.f;
    Xf[(size_t)w*KX + col] = f2b(v);
  }
}

// ---------------- zero-padding copy with f32->bf16 convert ----------------
__global__ void padcvt_kernel(const float* __restrict__ src, u16* __restrict__ dst,
                              int srows, int scols, int drows, int dcols)
{
  size_t i = (size_t)blockIdx.x*blockDim.x + threadIdx.x;
  size_t tot = (size_t)drows*dcols;
  if (i >= tot) return;
  int r = (int)(i / dcols), c = (int)(i % dcols);
  dst[i] = (r < srows && c < scols) ? f2b(src[(size_t)r*scols + c]) : (u16)0;
}

// ---------------- 128x128-tile bf16 MFMA GEMM: C = act(A[M,K] * B[N,K]^T) ----------------
template<int ACT>
__global__ __launch_bounds__(256)
void gemm_bt(const u16* __restrict__ A, const u16* __restrict__ Bm, u16* __restrict__ C,
             int M, int N, int K)
{
  __shared__ u16 As[128][40];
  __shared__ u16 Bs[128][40];
  const int bn0 = blockIdx.x * 128;
  const int bm0 = blockIdx.y * 128;
  const int tid = threadIdx.x;
  const int wid = tid >> 6, lane = tid & 63;
  const int q = lane >> 4, ln = lane & 15;
  const int moff = (wid >> 1) * 64, noff = (wid & 1) * 64;
  f32x4 acc[4][4];
  f32x4 z4 = {0.f,0.f,0.f,0.f};
  #pragma unroll
  for (int i=0;i<4;i++){ acc[i][0]=z4; acc[i][1]=z4; acc[i][2]=z4; acc[i][3]=z4; }

  const int c0 = tid*2;
  const int r0 = c0>>2, kc0 = (c0&3)*8;
  const int c1 = c0+1;
  const int r1 = c1>>2, kc1 = (c1&3)*8;

  for (int kk = 0; kk < K; kk += 32) {
    *(uint4*)&As[r0][kc0] = *(const uint4*)&A[(size_t)(bm0+r0)*K + kk + kc0];
    *(uint4*)&As[r1][kc1] = *(const uint4*)&A[(size_t)(bm0+r1)*K + kk + kc1];
    *(uint4*)&Bs[r0][kc0] = *(const uint4*)&Bm[(size_t)(bn0+r0)*K + kk + kc0];
    *(uint4*)&Bs[r1][kc1] = *(const uint4*)&Bm[(size_t)(bn0+r1)*K + kk + kc1];
    __syncthreads();
    s8v af[4], bf[4];
    #pragma unroll
    for (int i=0;i<4;i++) af[i] = *(const s8v*)&As[moff + 16*i + ln][q*8];
    #pragma unroll
    for (int j=0;j<4;j++) bf[j] = *(const s8v*)&Bs[noff + 16*j + ln][q*8];
    #pragma unroll
    for (int i=0;i<4;i++)
      #pragma unroll
      for (int j=0;j<4;j++)
        acc[i][j] = __builtin_amdgcn_mfma_f32_16x16x32_bf16(af[i], bf[j], acc[i][j], 0,0,0);
    __syncthreads();
  }
  #pragma unroll
  for (int i=0;i<4;i++){
    #pragma unroll
    for (int j=0;j<4;j++){
      #pragma unroll
      for (int r=0;r<4;r++){
        int m = bm0 + moff + 16*i + q*4 + r;
        int n = bn0 + noff + 16*j + ln;
        float v = acc[i][j][r];
        if (ACT == 1) v = ftanh(v);
        C[(size_t)m*N + n] = f2b(v);
      }
    }
  }
}

// ---------------- persistent bidirectional LSTM ----------------
// 64 blocks: [0,32) fwd, [32,64) bwd. Block owns 16 hidden units.
// R5 = R2(passing) + ONE change: the weight-operand swap.
//  * h-part weights (the 64KB slice R2 re-read from LDS every step: 256
//    ds_read_b128/CU/step ~0.85us + 8-way conflicts) now live in 256 VGPRs
//    per lane (bw[4][16]), loaded ONCE. h-phase is register-only MFMA.
//  * x-part weights moved to LDS (40KB, [frag][lane] linear = conflict-free);
//    their ds_reads run in the x-phase, inside the h-load latency shadow.
//  * x A-frags JIT-loaded per step via asm with an ALWAYS-VALID row: for bwd
//    t >= alen the reference consumes x[t] which embed_kernel already zeroed,
//    so row (t*64+b) is correct — no select, no zero page.
//  * Everything else identical to the R2 kernel that passed: __syncthreads
//    barriers, per-ks vmcnt(15-ks)+sched_barrier h-staging (rule 18), plain
//    cached HR full-line stores, h-exchange via sc0sc1 asm stores, vmcnt(0)
//    drain -> __syncthreads -> tid0 flag, poll guard 1<<20.
__global__ __launch_bounds__(256, 1)
void lstm_kernel(const float* __restrict__ Wih_f, const float* __restrict__ Whh_f,
                 const float* __restrict__ Wih_b, const float* __restrict__ Whh_b,
                 const u16* __restrict__ Xf, const int* __restrict__ lens_g,
                 u16* hbuf,                  // [2 dir][2][64][512] bf16
                 unsigned* __restrict__ HR,  // [2][32][4][512][4][32] u32 staging
                 unsigned* flags)            // [2][32] u32 (one per block)
{
  __shared__ s8v BxL[40][64];   // 40 KiB x-part B-frags: [gt*10+ks][lane]
  const int bid = blockIdx.x;
  const int dir = bid >> 5;
  const int blk = bid & 31;
  const int j0 = blk * 16;
  const int tid = threadIdx.x;
  const int wv = tid >> 6, lane = tid & 63;
  const int q = lane >> 4, ln = lane & 15;
  const float* Wih = dir ? Wih_b : Wih_f;
  const float* Whh = dir ? Whh_b : Whh_f;

  // x-part weight frags -> LDS (wave 0 builds; each lane builds its own frag)
  if (wv == 0) {
    #pragma unroll
    for (int gt=0; gt<4; gt++){
      #pragma unroll
      for (int ks=0; ks<10; ks++){
        int wrow = gt*HH + j0 + ln;
        int col0 = ks*32 + q*8;
        union { u16 h[8]; s8v v; } pk;
        #pragma unroll
        for (int e=0;e<8;e++){
          int col = col0 + e;
          pk.h[e] = (col < NINP) ? f2b(Wih[(size_t)wrow*NINP + col]) : (u16)0;
        }
        BxL[gt*10+ks][lane] = pk.v;
      }
    }
  }

  // h-part weight frags -> registers (256 VGPR): bw[gt][ks]; B n-row = gt*16+ln
  // maps to Whh row gt*512 + j0 + ln, k-cols ks*32 + q*8 .. +8 (same mapping
  // R2 used through its LDS slice).
  s8v bw[4][16];
  #pragma unroll
  for (int gt=0; gt<4; gt++){
    #pragma unroll
    for (int ks=0; ks<16; ks++){
      int wrow = gt*HH + j0 + ln;
      int col0 = ks*32 + q*8;
      const float4* wp = (const float4*)&Whh[(size_t)wrow*HH + col0];
      float4 a = wp[0], b = wp[1];
      union { unsigned u[4]; s8v v; } pk;
      pk.u[0] = (unsigned)f2b(a.x) | ((unsigned)f2b(a.y)<<16);
      pk.u[1] = (unsigned)f2b(a.z) | ((unsigned)f2b(a.w)<<16);
      pk.u[2] = (unsigned)f2b(b.x) | ((unsigned)f2b(b.y)<<16);
      pk.u[3] = (unsigned)f2b(b.z) | ((unsigned)f2b(b.w)<<16);
      bw[gt][ks] = pk.v;
    }
  }

  const int bat0 = wv*16;
  const int alen = lens_g[bat0 + ln];       // per-lane A-row length (bwd x rows)
  __syncthreads();

  float c_state[4] = {0.f,0.f,0.f,0.f};
  const int j = j0 + ln;

  u16* hb = hbuf + (size_t)dir*2*BT*HH;
  unsigned* myflags = flags + dir*32;       // 128 B per dir, its own lines

  for (int t = 0; t < TT; t++) {
    s8v xv[10];
    s8v hreg[16];
    if (t > 0) {
      // ---- wave 0 polls the 32 per-block flags (2 lines), others park ----
      if (wv == 0) {
        unsigned tgt = (unsigned)t;
        int guard = 0;
        for (;;) {
          unsigned v = (lane < 32)
            ? __hip_atomic_load(&myflags[lane], __ATOMIC_RELAXED, __HIP_MEMORY_SCOPE_AGENT)
            : tgt;
          if (__ballot(v >= tgt) == ~0ull) break;
          __builtin_amdgcn_s_sleep(1);
          if (++guard > (1<<20)) break;     // deadlock escape, never expected
        }
      }
      __syncthreads();   // releases waves 1-3; implicit full drain (HR acks etc.)
    }

    // x JIT loads: row is ALWAYS valid; bwd t>=alen reads row t (zeroed by embed)
    {
      int tr = (dir == 0) ? t : ((t < alen) ? (alen-1-t) : t);
      int xr = tr*BT + bat0 + ln;
      const u16* xp = Xf + (size_t)xr*KX + q*8;
      #pragma unroll
      for (int ks=0; ks<10; ks++)
        asm volatile("global_load_dwordx4 %0, %1, off offset:%2"
                     : "=v"(xv[ks]) : "v"(xp), "n"(ks*64) : "memory");
    }
    // h loads (cache-bypass, fresh from MALL); issued every t (t=0 values unused)
    {
      const u16* hp = hb + (size_t)(t & 1)*BT*HH + (size_t)(bat0 + ln)*HH + q*8;
      #pragma unroll
      for (int ks = 0; ks < 16; ks++)
        asm volatile("global_load_dwordx4 %0, %1, off offset:%2 sc0 sc1"
                     : "=v"(hreg[ks]) : "v"(hp), "n"(ks*64) : "memory");
    }

    f32x4 acc[4];
    f32x4 z4 = {0.f,0.f,0.f,0.f};
    #pragma unroll
    for (int gt=0; gt<4; gt++) acc[gt] = z4;

    // x-part: single wall (10 x loads done; 16 h loads still in flight), then
    // compiler freely pipelines the BxL ds_reads + 40 MFMAs
    asm volatile("s_waitcnt vmcnt(16)" ::: "memory");
    __builtin_amdgcn_sched_barrier(0);
    #pragma unroll
    for (int ks=0; ks<10; ks++){
      #pragma unroll
      for (int gt=0; gt<4; gt++){
        s8v bxf = BxL[gt*10+ks][lane];
        acc[gt] = __builtin_amdgcn_mfma_f32_16x16x32_bf16(xv[ks], bxf, acc[gt], 0,0,0);
      }
    }
    // h-part: PURE REGISTER MFMAs (bw resident), per-ks exact waits (R2 pattern)
    if (t > 0) {
      #pragma unroll
      for (int ks=0; ks<16; ks++) {
        asm volatile("s_waitcnt vmcnt(%0)" :: "n"(15-ks) : "memory");
        __builtin_amdgcn_sched_barrier(0);   // rule 18
        #pragma unroll
        for (int gt=0; gt<4; gt++)
          acc[gt] = __builtin_amdgcn_mfma_f32_16x16x32_bf16(hreg[ks], bw[gt][ks], acc[gt], 0,0,0);
      }
    }

    // gates -> h
    u16 hv4[4];
    #pragma unroll
    for (int r=0;r<4;r++) {
      float iv = 1.f/(1.f + __expf(-acc[0][r]));
      float fv = 1.f/(1.f + __expf(-acc[1][r]));
      float gv = ftanh(acc[2][r]);
      float ov = 1.f/(1.f + __expf(-acc[3][r]));
      float cc = fv*c_state[r] + iv*gv;
      c_state[r] = cc;
      hv4[r] = f2b(ov*ftanh(cc));
    }
    // pair-pack (even ln lanes hold u32 covering j, j+1)
    unsigned pk4[4];
    #pragma unroll
    for (int r=0;r<4;r++) {
      unsigned lo = hv4[r];
      unsigned partner = (unsigned)__shfl((int)lo, lane ^ 1);
      pk4[r] = lo | (partner << 16);
    }
    const bool evn = ((ln & 1) == 0);

    // HR stores: per (wv,r) one wave-instruction writes one full 128B line,
    // sole-owner, plain cached. Repack kernel produces Hout afterwards.
    {
      size_t base = (((size_t)(dir*32 + blk)*4 + wv)*512 + (size_t)t)*4;
      if (evn) {
        #pragma unroll
        for (int r=0;r<4;r++)
          HR[(base + r)*32 + q*8 + (ln>>1)] = pk4[r];
      }
    }
    if (t < TT-1) {
      // h exchange: explicit write-through (sc0 sc1) stores to MALL
      if (evn) {
        u16* hnxt = hb + (size_t)((t+1)&1)*BT*HH;
        #pragma unroll
        for (int r=0;r<4;r++) {
          int bat = bat0 + q*4 + r;
          unsigned* dst = (unsigned*)(hnxt + (size_t)bat*HH + j);
          asm volatile("global_store_dword %0, %1, off sc0 sc1"
                       :: "v"(dst), "v"(pk4[r]) : "memory");
        }
      }
      // drain ALL outstanding vmem (h stores at MALL, HR acked)
      asm volatile("s_waitcnt vmcnt(0)" ::: "memory");
      __syncthreads();
      // relaxed write-through flag: safe because h stores are already at the
      // coherence point (no release fence -> no per-step cache writeback)
      if (tid == 0) {
        unsigned* fp = &myflags[blk];
        unsigned fv = (unsigned)(t+1);
        asm volatile("global_store_dword %0, %1, off sc0 sc1"
                     :: "v"(fp), "v"(fv) : "memory");
      }
    }
  }
}

// ---------------- repack HR -> Hout [b][tp][dir*512+j] (applies bwd reversal) ----------------
__global__ __launch_bounds__(256)
void repack_kernel(const unsigned* __restrict__ HR, const int* __restrict__ lens,
                   u16* __restrict__ Hout)
{
  int w = blockIdx.x*4 + (threadIdx.x>>6);   // 0..65535 : (dir,b,t)
  int lane = threadIdx.x & 63;
  int dir = w >> 15;
  int b   = (w >> 9) & 63;
  int t   = w & 511;
  int len = lens[b];
  int tp = t;
  if (dir) tp = (t < len) ? (len - 1 - t) : t;
  int blk = lane >> 1;
  int wv = b >> 4, q = (b >> 2) & 3, r = b & 3;
  size_t src = ((((size_t)(dir*32 + blk)*4 + wv)*512 + (size_t)t)*4 + r)*32
               + q*8 + (lane & 1)*4;
  uint4 v = *(const uint4*)&HR[src];
  *(uint4*)&Hout[((size_t)b*TT + tp)*H2 + dir*HH + lane*8] = v;
}

// ---------------- masked softmax over T per (b,r) row ----------------
__global__ __launch_bounds__(256)
void softmax_kernel(const u16* __restrict__ s2, const int* __restrict__ lens,
                    float* __restrict__ A)
{
  int w = blockIdx.x*4 + (threadIdx.x>>6);   // 0..1919
  int lane = threadIdx.x & 63;
  int b = w / RR, r = w % RR;
  int len = lens[b];
  float v[8];
  float mx = -1e38f;
  #pragma unroll
  for (int i=0;i<8;i++){
    int t = lane + i*64;
    float x = b2f(s2[((size_t)b*TT + t)*RP + r]);
    v[i] = (t < len) ? x : -1e38f;
    mx = fmaxf(mx, v[i]);
  }
  #pragma unroll
  for (int o=1;o<64;o<<=1) mx = fmaxf(mx, __shfl_xor(mx, o));
  float sm = 0.f;
  #pragma unroll
  for (int i=0;i<8;i++){ v[i] = __expf(v[i]-mx); sm += v[i]; }
  #pragma unroll
  for (int o=1;o<64;o<<=1) sm += __shfl_xor(sm, o);
  float inv = 1.0f/sm;
  #pragma unroll
  for (int i=0;i<8;i++){
    int t = lane + i*64;
    A[((size_t)b*RR + r)*TT + t] = v[i]*inv;
  }
}

// ---------------- penal = mean_b ||A A^T - I||_F^2 ----------------
__global__ __launch_bounds__(256)
void penal_kernel(const float* __restrict__ A, float* __restrict__ pen)
{
  __shared__ __align__(16) float Af[RR*TT];
  __shared__ float red[4];
  int b = blockIdx.x, tid = threadIdx.x;
  for (int i=tid;i<RR*TT;i+=256) Af[i] = A[(size_t)b*RR*TT + i];
  __syncthreads();
  float s = 0.f;
  for (int p = tid; p < RR*RR; p += 256) {
    int r = p/RR, c = p%RR;
    float d = 0.f;
    for (int t=0;t<TT;t++) d += Af[r*TT+t]*Af[c*TT+t];
    d -= (r==c) ? 1.f : 0.f;
    s += d*d;
  }
  #pragma unroll
  for (int o=1;o<64;o<<=1) s += __shfl_xor(s, o);
  if ((tid&63)==0) red[tid>>6] = s;
  __syncthreads();
  if (tid==0) atomicAdd(pen, (red[0]+red[1]+red[2]+red[3]) * (1.0f/64.0f));
}

// ---------------- M = einsum('brt,bth->brh', A, Hout), bf16 out ----------------
__global__ __launch_bounds__(256)
void attnM_kernel(const float* __restrict__ A, const u16* __restrict__ Hout,
                  u16* __restrict__ Mout)
{
  __shared__ __align__(16) float Af[RR*TT];
  int b = blockIdx.x >> 2;
  int ch = blockIdx.x & 3;
  int tid = threadIdx.x;
  for (int i=tid;i<RR*TT;i+=256) Af[i] = A[(size_t)b*RR*TT + i];
  __syncthreads();
  int h = ch*256 + tid;
  float m[RR];
  #pragma unroll
  for (int r=0;r<RR;r++) m[r] = 0.f;
  for (int t=0;t<TT;t+=4){
    float hv0 = b2f(Hout[((size_t)b*TT + t+0)*H2 + h]);
    float hv1 = b2f(Hout[((size_t)b*TT + t+1)*H2 + h]);
    float hv2 = b2f(Hout[((size_t)b*TT + t+2)*H2 + h]);
    float hv3 = b2f(Hout[((size_t)b*TT + t+3)*H2 + h]);
    #pragma unroll
    for (int r=0;r<RR;r++){
      f32x4 a4 = *(const f32x4*)&Af[r*TT + t];
      m[r] += a4.x*hv0 + a4.y*hv1 + a4.z*hv2 + a4.w*hv3;
    }
  }
  #pragma unroll
  for (int r=0;r<RR;r++) Mout[((size_t)b*RR + r)*H2 + h] = f2b(m[r]);
}

// ---------------- R1 += BM @ Wm^T partials (K-split x8); relu+bias in dec ----------------
__global__ __launch_bounds__(256)
void mlp1_kernel(const u16* __restrict__ BM, const float* __restrict__ Wm,
                 float* __restrict__ R1)
{
  int kc = blockIdx.x >> 5;                 // 0..7 K-chunk
  int xb = blockIdx.x & 31;
  int w = xb*4 + (threadIdx.x>>6);
  if (w >= MLPH/16) return;                 // 125 waves per K-chunk
  int lane = threadIdx.x & 63;
  int q = lane>>4, ln = lane&15;
  f32x4 z4 = {0.f,0.f,0.f,0.f};
  f32x4 acc[4] = {z4,z4,z4,z4};
  const float* wrow = Wm + (size_t)(w*16 + ln)*KMLP;
  for (int ks = kc*KCH; ks < (kc+1)*KCH; ks += 32){
    s8v bf = cvt8t(&wrow[ks + q*8]);
    #pragma unroll
    for (int i=0;i<4;i++){
      s8v af = *(const s8v*)&BM[(size_t)(i*16+ln)*KMLP + ks + q*8];
      acc[i] = __builtin_amdgcn_mfma_f32_16x16x32_bf16(af, bf, acc[i], 0,0,0);
    }
  }
  int n = w*16 + ln;
  #pragma unroll
  for (int i=0;i<4;i++){
    #pragma unroll
    for (int r=0;r<4;r++){
      int m = i*16 + q*4 + r;
      atomicAdd(&R1[(size_t)m*MLPH + n], acc[i][r]);
    }
  }
}

// ---------------- decoded = relu(R1+bm) @ Wd^T + bd, wave per output ----------------
__global__ __launch_bounds__(256)
void dec_kernel(const float* __restrict__ R1, const float* __restrict__ bm,
                const float* __restrict__ Wd, const float* __restrict__ bd,
                float* __restrict__ dec)
{
  int w = blockIdx.x*4 + (threadIdx.x>>6);   // 0..319
  int lane = threadIdx.x & 63;
  int m = w/5, n = w%5;
  float s = 0.f;
  for (int k=lane;k<MLPH;k+=64){
    float v = R1[(size_t)m*MLPH+k] + bm[k];
    s += fmaxf(v, 0.f)*Wd[(size_t)n*MLPH+k];
  }
  #pragma unroll
  for (int o=1;o<64;o<<=1) s += __shfl_xor(s, o);
  if (lane==0) dec[m*5+n] = s + bd[n];
}

__global__ __launch_bounds__(384)
void fin_kernel(const float* __restrict__ dec, const float* __restrict__ pen,
                float* __restrict__ out)
{
  int i = threadIdx.x;
  if (i < 320) out[i] = dec[i];
  if (i == 320) out[320] = *pen;
}

__global__ void zero_out_kernel(float* out){ int i = blockIdx.x*256 + threadIdx.x; if (i < 321) out[i] = 0.f; }

extern "C" void kernel_launch(void* const* d_in, const int* in_sizes, int n_in,
                              void* d_out, int out_size, void* d_ws, size_t ws_size,
                              hipStream_t stream)
{
  const int*   ids  = (const int*)d_in[0];
  const int*   lens = (const int*)d_in[1];
  const float* emb  = (const float*)d_in[2];
  const float* Wihf = (const float*)d_in[3];
  const float* Whhf = (const float*)d_in[4];
  const float* Wihb = (const float*)d_in[5];
  const float* Whhb = (const float*)d_in[6];
  const float* W1   = (const float*)d_in[7];
  const float* W2   = (const float*)d_in[8];
  const float* Wm   = (const float*)d_in[9];
  const float* bm   = (const float*)d_in[10];
  const float* Wd   = (const float*)d_in[11];
  const float* bd   = (const float*)d_in[12];

  char* ws = (char*)d_ws;
  size_t off = 0;
  auto nxt = [&](size_t sz){ size_t r = off; off += (sz + 255) & ~(size_t)255; return r; };
  const size_t HRsz = (size_t)2*32*4*512*4*32*4;   // 67,108,864 B
  size_t oZ   = nxt(4096);
  size_t oXf  = nxt((size_t)MROWS*KX*2);
  size_t oHout= nxt((size_t)BT*TT*H2*2);
  size_t oW1p = nxt((size_t)DAP*H2*2);
  size_t oW2p = nxt((size_t)RP*DAP*2);
  size_t oHb  = nxt((size_t)2*2*BT*HH*2);
  // HR aliases the phase-2 buffers (s1/s2/A/M/R1/dec): HR is dead after repack,
  // phase-2 buffers are written only after repack.
  size_t oBig = nxt(HRsz);
  size_t p2 = oBig;
  auto sub = [&](size_t sz){ size_t r = p2; p2 += (sz + 255) & ~(size_t)255; return r; };
  size_t oS1  = sub((size_t)MROWS*DAP*2);
  size_t oS2  = sub((size_t)MROWS*RP*2);
  size_t oA   = sub((size_t)BT*RR*TT*4);
  size_t oM   = sub((size_t)BT*RR*H2*2);
  size_t oR1  = sub((size_t)BT*MLPH*4);
  size_t oDec = sub(2048);
  size_t need = off;          // phase-2 total (41.9MB) < HRsz, stays inside oBig

  if (ws_size < need) {           // fail loudly (deterministic zeros), no OOB writes
    zero_out_kernel<<<2, 256, 0, stream>>>((float*)d_out);
    return;
  }

  u16* Xf    = (u16*)(ws + oXf);
  u16* Hout  = (u16*)(ws + oHout);
  u16* W1p   = (u16*)(ws + oW1p);
  u16* W2p   = (u16*)(ws + oW2p);
  u16* hb    = (u16*)(ws + oHb);
  unsigned* HR = (unsigned*)(ws + oBig);
  u16* s1    = (u16*)(ws + oS1);
  u16* s2    = (u16*)(ws + oS2);
  float* Ab  = (float*)(ws + oA);
  u16* Mo    = (u16*)(ws + oM);
  float* R1  = (float*)(ws + oR1);
  float* dec = (float*)(ws + oDec);
  unsigned* flags = (unsigned*)(ws + oZ);
  float* pen = (float*)(ws + oZ + 2048);

  hipMemsetAsync(ws + oZ, 0, 4096, stream);            // flags + penal accumulator

  embed_kernel<<<8192, 256, 0, stream>>>(ids, lens, emb, Xf);
  padcvt_kernel<<<(DAP*H2+255)/256, 256, 0, stream>>>(W1, W1p, 350, H2, DAP, H2);
  padcvt_kernel<<<(RP*DAP+255)/256, 256, 0, stream>>>(W2, W2p, RR, 350, RP, DAP);

  lstm_kernel<<<64, 256, 0, stream>>>(Wihf, Whhf, Wihb, Whhb, Xf, lens, hb, HR, flags);

  repack_kernel<<<16384, 256, 0, stream>>>(HR, lens, Hout);

  // R1 zero AFTER repack is enqueued (R1 aliases HR region; memset here is
  // stream-ordered after repack completes reading HR)
  hipMemsetAsync(ws + oR1, 0, (size_t)BT*MLPH*4, stream);

  dim3 gS1(DAP/128, MROWS/128);
  gemm_bt<1><<<gS1, 256, 0, stream>>>(Hout, W1p, s1, MROWS, DAP, H2);
  dim3 gS2(RP/128, MROWS/128);
  gemm_bt<0><<<gS2, 256, 0, stream>>>(s1, W2p, s2, MROWS, RP, DAP);

  softmax_kernel<<<480, 256, 0, stream>>>(s2, lens, Ab);
  penal_kernel<<<64, 256, 0, stream>>>(Ab, pen);
  attnM_kernel<<<256, 256, 0, stream>>>(Ab, Hout, Mo);
  mlp1_kernel<<<256, 256, 0, stream>>>(Mo, Wm, R1);
  dec_kernel<<<80, 256, 0, stream>>>(R1, bm, Wd, bd, dec);
  fin_kernel<<<1, 384, 0, stream>>>(dec, pen, (float*)d_out);
  (void)in_sizes; (void)n_in; (void)out_size; (void)ws_size;
}

// Round 6
// 3356.112 us; speedup vs baseline: 1.1761x; 1.1761x over previous
//
#include <hip/hip_runtime.h>
#include <stdint.h>

typedef unsigned short u16;
typedef unsigned long long u64;
typedef short s8v __attribute__((ext_vector_type(8)));
typedef float f32x4 __attribute__((ext_vector_type(4)));

#define BT    64
#define TT    512
#define NINP  300
#define KX    320
#define HH    512
#define DAP   384
#define RR    30
#define RP    128
#define MROWS 32768
#define MLPH  2000
#define H2    1024
#define KSPL  8
#define KMLP  30720
#define KCH   (KMLP/KSPL)   // 3840

__device__ inline float b2f(u16 u){ union{unsigned i; float f;} v; v.i = ((unsigned)u)<<16; return v.f; }
__device__ inline u16 f2b(float x){ union{unsigned i; float f;} v; v.f = x; unsigned b = v.i;
  unsigned r = (b + 0x7fffu + ((b>>16)&1u))>>16; return (u16)r; }

// fast tanh: 1 - 2/(e^{2x}+1). Exact at +-inf, ~1e-6 rel err; bf16-safe.
__device__ inline float ftanh(float x){
  float e = __expf(2.f*x);
  return 1.f - 2.f/(e + 1.f);
}

// truncating f32x8 -> bf16x8 pack (streaming Wm)
__device__ inline s8v cvt8t(const float* p){
  union { unsigned u[4]; s8v v; } r;
  #pragma unroll
  for (int i=0;i<4;i++){
    unsigned lo = __float_as_uint(p[2*i])   >> 16;
    unsigned hi = __float_as_uint(p[2*i+1]) & 0xFFFF0000u;
    r.u[i] = lo | hi;
  }
  return r.v;
}

// ---------------- embedding gather f32->bf16 (+mask), t-major rows r = t*64+b ----------------
__global__ __launch_bounds__(256)
void embed_kernel(const int* __restrict__ ids, const int* __restrict__ lens,
                  const float* __restrict__ emb, u16* __restrict__ Xf)
{
  int w = blockIdx.x*4 + (threadIdx.x>>6);  // row 0..32767
  int lane = threadIdx.x & 63;
  int b = w & 63, t = w >> 6;
  int len = lens[b];
  int id = ids[b*TT + t];
  bool valid = t < len;
  const float* src = emb + (size_t)id*NINP;
  #pragma unroll
  for (int i=0;i<5;i++){
    int col = lane + i*64;
    float v = (valid && col < NINP) ? src[col] : 0.f;
    Xf[(size_t)w*KX + col] = f2b(v);
  }
}

// ---------------- zero-padding copy with f32->bf16 convert ----------------
__global__ void padcvt_kernel(const float* __restrict__ src, u16* __restrict__ dst,
                              int srows, int scols, int drows, int dcols)
{
  size_t i = (size_t)blockIdx.x*blockDim.x + threadIdx.x;
  size_t tot = (size_t)drows*dcols;
  if (i >= tot) return;
  int r = (int)(i / dcols), c = (int)(i % dcols);
  dst[i] = (r < srows && c < scols) ? f2b(src[(size_t)r*scols + c]) : (u16)0;
}

// ---------------- 128x128-tile bf16 MFMA GEMM: C = act(A[M,K] * B[N,K]^T) ----------------
template<int ACT>
__global__ __launch_bounds__(256)
void gemm_bt(const u16* __restrict__ A, const u16* __restrict__ Bm, u16* __restrict__ C,
             int M, int N, int K)
{
  __shared__ u16 As[128][40];
  __shared__ u16 Bs[128][40];
  const int bn0 = blockIdx.x * 128;
  const int bm0 = blockIdx.y * 128;
  const int tid = threadIdx.x;
  const int wid = tid >> 6, lane = tid & 63;
  const int q = lane >> 4, ln = lane & 15;
  const int moff = (wid >> 1) * 64, noff = (wid & 1) * 64;
  f32x4 acc[4][4];
  f32x4 z4 = {0.f,0.f,0.f,0.f};
  #pragma unroll
  for (int i=0;i<4;i++){ acc[i][0]=z4; acc[i][1]=z4; acc[i][2]=z4; acc[i][3]=z4; }

  const int c0 = tid*2;
  const int r0 = c0>>2, kc0 = (c0&3)*8;
  const int c1 = c0+1;
  const int r1 = c1>>2, kc1 = (c1&3)*8;

  for (int kk = 0; kk < K; kk += 32) {
    *(uint4*)&As[r0][kc0] = *(const uint4*)&A[(size_t)(bm0+r0)*K + kk + kc0];
    *(uint4*)&As[r1][kc1] = *(const uint4*)&A[(size_t)(bm0+r1)*K + kk + kc1];
    *(uint4*)&Bs[r0][kc0] = *(const uint4*)&Bm[(size_t)(bn0+r0)*K + kk + kc0];
    *(uint4*)&Bs[r1][kc1] = *(const uint4*)&Bm[(size_t)(bn0+r1)*K + kk + kc1];
    __syncthreads();
    s8v af[4], bf[4];
    #pragma unroll
    for (int i=0;i<4;i++) af[i] = *(const s8v*)&As[moff + 16*i + ln][q*8];
    #pragma unroll
    for (int j=0;j<4;j++) bf[j] = *(const s8v*)&Bs[noff + 16*j + ln][q*8];
    #pragma unroll
    for (int i=0;i<4;i++)
      #pragma unroll
      for (int j=0;j<4;j++)
        acc[i][j] = __builtin_amdgcn_mfma_f32_16x16x32_bf16(af[i], bf[j], acc[i][j], 0,0,0);
    __syncthreads();
  }
  #pragma unroll
  for (int i=0;i<4;i++){
    #pragma unroll
    for (int j=0;j<4;j++){
      #pragma unroll
      for (int r=0;r<4;r++){
        int m = bm0 + moff + 16*i + q*4 + r;
        int n = bn0 + noff + 16*j + ln;
        float v = acc[i][j][r];
        if (ACT == 1) v = ftanh(v);
        C[(size_t)m*N + n] = f2b(v);
      }
    }
  }
}

// ---------------- persistent bidirectional LSTM ----------------
// 64 blocks: [0,32) fwd, [32,64) bwd. Block owns 16 hidden units.
// R6 = R5(passing) + restored cross-step x-prefetch pipeline (the isolated
// R2->R5 regression: x JIT-loaded after the barrier exposed ~1us/step of
// MALL latency + wall serialization before the first MFMA).
//  * h-part weights in 256 regs (bw[4][16], loaded once); x-part weights in
//    LDS (40KB [frag][lane], conflict-free) -- unchanged from R5.
//  * x A-frags for step t+1 are prefetched in the tail of step t (asm loads,
//    registers survive the barrier). At step top only the 16 h-loads matter.
//  * Tail order: h-stores(4, sc0sc1) -> HR(4, plain asm) -> x-prefetch(10)
//    -> vmcnt(14) [drains exactly the h-stores; at t=0 also the 16 stale
//    h-loads: 34-14=20=16+4] -> RAW s_barrier (no auto-drain; HR acks + x
//    stay in flight) -> tid0 flag (sc0sc1).
//  * Top: wave0 polls (its compiler-emitted vmcnt(0) drains leftovers during
//    the wait), raw s_barrier, issue h(16, sc0sc1), vmcnt(16) wall (drains
//    leftover HR+x for waves1-3; x completed during tail+poll -> ~free),
//    x MFMAs immediately (xv in regs), then per-ks h waits vmcnt(15-ks)
//    + sched_barrier(0) (rule 18) -- ends at vmcnt(0) so tail starts clean.
//  * Post-loop vmcnt(0): HR stores complete before endpgm (repack reads them).
__global__ __launch_bounds__(256, 1)
void lstm_kernel(const float* __restrict__ Wih_f, const float* __restrict__ Whh_f,
                 const float* __restrict__ Wih_b, const float* __restrict__ Whh_b,
                 const u16* __restrict__ Xf, const int* __restrict__ lens_g,
                 u16* hbuf,                  // [2 dir][2][64][512] bf16
                 unsigned* __restrict__ HR,  // [2][32][4][512][4][32] u32 staging
                 unsigned* flags)            // [2][32] u32 (one per block)
{
  __shared__ s8v BxL[40][64];   // 40 KiB x-part B-frags: [gt*10+ks][lane]
  const int bid = blockIdx.x;
  const int dir = bid >> 5;
  const int blk = bid & 31;
  const int j0 = blk * 16;
  const int tid = threadIdx.x;
  const int wv = tid >> 6, lane = tid & 63;
  const int q = lane >> 4, ln = lane & 15;
  const float* Wih = dir ? Wih_b : Wih_f;
  const float* Whh = dir ? Whh_b : Whh_f;

  // x-part weight frags -> LDS (wave 0 builds; each lane builds its own frag)
  if (wv == 0) {
    #pragma unroll
    for (int gt=0; gt<4; gt++){
      #pragma unroll
      for (int ks=0; ks<10; ks++){
        int wrow = gt*HH + j0 + ln;
        int col0 = ks*32 + q*8;
        union { u16 h[8]; s8v v; } pk;
        #pragma unroll
        for (int e=0;e<8;e++){
          int col = col0 + e;
          pk.h[e] = (col < NINP) ? f2b(Wih[(size_t)wrow*NINP + col]) : (u16)0;
        }
        BxL[gt*10+ks][lane] = pk.v;
      }
    }
  }

  // h-part weight frags -> registers (256 VGPR): bw[gt][ks]; B n-row = gt*16+ln
  s8v bw[4][16];
  #pragma unroll
  for (int gt=0; gt<4; gt++){
    #pragma unroll
    for (int ks=0; ks<16; ks++){
      int wrow = gt*HH + j0 + ln;
      int col0 = ks*32 + q*8;
      const float4* wp = (const float4*)&Whh[(size_t)wrow*HH + col0];
      float4 a = wp[0], b = wp[1];
      union { unsigned u[4]; s8v v; } pk;
      pk.u[0] = (unsigned)f2b(a.x) | ((unsigned)f2b(a.y)<<16);
      pk.u[1] = (unsigned)f2b(a.z) | ((unsigned)f2b(a.w)<<16);
      pk.u[2] = (unsigned)f2b(b.x) | ((unsigned)f2b(b.y)<<16);
      pk.u[3] = (unsigned)f2b(b.z) | ((unsigned)f2b(b.w)<<16);
      bw[gt][ks] = pk.v;
    }
  }

  const int bat0 = wv*16;
  const int alen = lens_g[bat0 + ln];       // per-lane A-row length (bwd x rows)
  __syncthreads();   // init drain: loop entry has 0 outstanding vmem

  float c_state[4] = {0.f,0.f,0.f,0.f};
  const int j = j0 + ln;

  u16* hb = hbuf + (size_t)dir*2*BT*HH;
  unsigned* myflags = flags + dir*32;       // 128 B per dir, its own lines

  // prologue: prefetch x for t=0 (alen >= 1 guaranteed)
  s8v xv[10];
  {
    int tr = (dir == 0) ? 0 : (alen - 1);
    int xr = tr*BT + bat0 + ln;
    const u16* xp = Xf + (size_t)xr*KX + q*8;
    #pragma unroll
    for (int ks=0; ks<10; ks++)
      asm volatile("global_load_dwordx4 %0, %1, off offset:%2"
                   : "=v"(xv[ks]) : "v"(xp), "n"(ks*64) : "memory");
  }

  for (int t = 0; t < TT; t++) {
    s8v hreg[16];
    if (t > 0) {
      // ---- wave 0 polls the 32 per-block flags (2 lines), others park ----
      if (wv == 0) {
        unsigned tgt = (unsigned)t;
        int guard = 0;
        for (;;) {
          unsigned v = (lane < 32)
            ? __hip_atomic_load(&myflags[lane], __ATOMIC_RELAXED, __HIP_MEMORY_SCOPE_AGENT)
            : tgt;
          if (__ballot(v >= tgt) == ~0ull) break;
          __builtin_amdgcn_s_sleep(1);
          if (++guard > (1<<20)) break;     // deadlock escape, never expected
        }
      }
      __builtin_amdgcn_s_barrier();
    }

    // h loads (cache-bypass, fresh from MALL); issued every t (t=0 values unused)
    {
      const u16* hp = hb + (size_t)(t & 1)*BT*HH + (size_t)(bat0 + ln)*HH + q*8;
      #pragma unroll
      for (int ks = 0; ks < 16; ks++)
        asm volatile("global_load_dwordx4 %0, %1, off offset:%2 sc0 sc1"
                     : "=v"(hreg[ks]) : "v"(hp), "n"(ks*64) : "memory");
    }

    // wall: leave exactly the 16 h-loads outstanding (drains prev-tail HR+x;
    // those completed during the tail/poll window -> near-free)
    asm volatile("s_waitcnt vmcnt(16)" ::: "memory");
    __builtin_amdgcn_sched_barrier(0);

    f32x4 acc[4];
    f32x4 z4 = {0.f,0.f,0.f,0.f};
    #pragma unroll
    for (int gt=0; gt<4; gt++) acc[gt] = z4;

    // x-part: xv already in regs; compiler pipelines BxL ds_reads + 40 MFMAs
    #pragma unroll
    for (int ks=0; ks<10; ks++){
      #pragma unroll
      for (int gt=0; gt<4; gt++){
        s8v bxf = BxL[gt*10+ks][lane];
        acc[gt] = __builtin_amdgcn_mfma_f32_16x16x32_bf16(xv[ks], bxf, acc[gt], 0,0,0);
      }
    }
    // h-part: PURE REGISTER MFMAs (bw resident), per-ks exact waits
    if (t > 0) {
      #pragma unroll
      for (int ks=0; ks<16; ks++) {
        asm volatile("s_waitcnt vmcnt(%0)" :: "n"(15-ks) : "memory");
        __builtin_amdgcn_sched_barrier(0);   // rule 18
        #pragma unroll
        for (int gt=0; gt<4; gt++)
          acc[gt] = __builtin_amdgcn_mfma_f32_16x16x32_bf16(hreg[ks], bw[gt][ks], acc[gt], 0,0,0);
      }
    }

    // gates -> h
    u16 hv4[4];
    #pragma unroll
    for (int r=0;r<4;r++) {
      float iv = 1.f/(1.f + __expf(-acc[0][r]));
      float fv = 1.f/(1.f + __expf(-acc[1][r]));
      float gv = ftanh(acc[2][r]);
      float ov = 1.f/(1.f + __expf(-acc[3][r]));
      float cc = fv*c_state[r] + iv*gv;
      c_state[r] = cc;
      hv4[r] = f2b(ov*ftanh(cc));
    }
    // pair-pack (even ln lanes hold u32 covering j, j+1)
    unsigned pk4[4];
    #pragma unroll
    for (int r=0;r<4;r++) {
      unsigned lo = hv4[r];
      unsigned partner = (unsigned)__shfl((int)lo, lane ^ 1);
      pk4[r] = lo | (partner << 16);
    }
    const bool evn = ((ln & 1) == 0);

    // --- tail: h-stores first (oldest on vmcnt), then HR, then x-prefetch ---
    if (t < TT-1 && evn) {
      u16* hnxt = hb + (size_t)((t+1)&1)*BT*HH;
      #pragma unroll
      for (int r=0;r<4;r++) {
        int bat = bat0 + q*4 + r;
        unsigned* dst = (unsigned*)(hnxt + (size_t)bat*HH + j);
        asm volatile("global_store_dword %0, %1, off sc0 sc1"
                     :: "v"(dst), "v"(pk4[r]) : "memory");
      }
    }
    // HR stores: per (wv,r) one wave-instruction writes one full 128B line
    if (evn) {
      size_t base = (((size_t)(dir*32 + blk)*4 + wv)*512 + (size_t)t)*4;
      #pragma unroll
      for (int r=0;r<4;r++){
        unsigned* hrp = &HR[(base + r)*32 + q*8 + (ln>>1)];
        asm volatile("global_store_dword %0, %1, off"
                     :: "v"(hrp), "v"(pk4[r]) : "memory");
      }
    }
    // x prefetch for t+1 (cached loads; latency hides under barrier+poll)
    {
      int tn = (t < TT-1) ? (t+1) : t;
      int tr = (dir == 0) ? tn : ((tn < alen) ? (alen-1-tn) : tn);
      int xr = tr*BT + bat0 + ln;
      const u16* xp = Xf + (size_t)xr*KX + q*8;
      #pragma unroll
      for (int ks=0; ks<10; ks++)
        asm volatile("global_load_dwordx4 %0, %1, off offset:%2"
                     : "=v"(xv[ks]) : "v"(xp), "n"(ks*64) : "memory");
    }
    if (t < TT-1) {
      // drain exactly the h-stores (t=0: also the 16 stale h-loads, 34->14)
      asm volatile("s_waitcnt vmcnt(14)" ::: "memory");
      __builtin_amdgcn_s_barrier();     // raw: HR acks + x-prefetch stay in flight
      if (tid == 0) {
        unsigned* fp = &myflags[blk];
        unsigned fv = (unsigned)(t+1);
        asm volatile("global_store_dword %0, %1, off sc0 sc1"
                     :: "v"(fp), "v"(fv) : "memory");
      }
    }
  }
  // HR stores (and final x loads) must complete before endpgm: repack reads HR
  asm volatile("s_waitcnt vmcnt(0)" ::: "memory");
}

// ---------------- repack HR -> Hout [b][tp][dir*512+j] (applies bwd reversal) ----------------
__global__ __launch_bounds__(256)
void repack_kernel(const unsigned* __restrict__ HR, const int* __restrict__ lens,
                   u16* __restrict__ Hout)
{
  int w = blockIdx.x*4 + (threadIdx.x>>6);   // 0..65535 : (dir,b,t)
  int lane = threadIdx.x & 63;
  int dir = w >> 15;
  int b   = (w >> 9) & 63;
  int t   = w & 511;
  int len = lens[b];
  int tp = t;
  if (dir) tp = (t < len) ? (len - 1 - t) : t;
  int blk = lane >> 1;
  int wv = b >> 4, q = (b >> 2) & 3, r = b & 3;
  size_t src = ((((size_t)(dir*32 + blk)*4 + wv)*512 + (size_t)t)*4 + r)*32
               + q*8 + (lane & 1)*4;
  uint4 v = *(const uint4*)&HR[src];
  *(uint4*)&Hout[((size_t)b*TT + tp)*H2 + dir*HH + lane*8] = v;
}

// ---------------- masked softmax over T per (b,r) row ----------------
__global__ __launch_bounds__(256)
void softmax_kernel(const u16* __restrict__ s2, const int* __restrict__ lens,
                    float* __restrict__ A)
{
  int w = blockIdx.x*4 + (threadIdx.x>>6);   // 0..1919
  int lane = threadIdx.x & 63;
  int b = w / RR, r = w % RR;
  int len = lens[b];
  float v[8];
  float mx = -1e38f;
  #pragma unroll
  for (int i=0;i<8;i++){
    int t = lane + i*64;
    float x = b2f(s2[((size_t)b*TT + t)*RP + r]);
    v[i] = (t < len) ? x : -1e38f;
    mx = fmaxf(mx, v[i]);
  }
  #pragma unroll
  for (int o=1;o<64;o<<=1) mx = fmaxf(mx, __shfl_xor(mx, o));
  float sm = 0.f;
  #pragma unroll
  for (int i=0;i<8;i++){ v[i] = __expf(v[i]-mx); sm += v[i]; }
  #pragma unroll
  for (int o=1;o<64;o<<=1) sm += __shfl_xor(sm, o);
  float inv = 1.0f/sm;
  #pragma unroll
  for (int i=0;i<8;i++){
    int t = lane + i*64;
    A[((size_t)b*RR + r)*TT + t] = v[i]*inv;
  }
}

// ---------------- penal = mean_b ||A A^T - I||_F^2 ----------------
__global__ __launch_bounds__(256)
void penal_kernel(const float* __restrict__ A, float* __restrict__ pen)
{
  __shared__ __align__(16) float Af[RR*TT];
  __shared__ float red[4];
  int b = blockIdx.x, tid = threadIdx.x;
  for (int i=tid;i<RR*TT;i+=256) Af[i] = A[(size_t)b*RR*TT + i];
  __syncthreads();
  float s = 0.f;
  for (int p = tid; p < RR*RR; p += 256) {
    int r = p/RR, c = p%RR;
    float d = 0.f;
    for (int t=0;t<TT;t++) d += Af[r*TT+t]*Af[c*TT+t];
    d -= (r==c) ? 1.f : 0.f;
    s += d*d;
  }
  #pragma unroll
  for (int o=1;o<64;o<<=1) s += __shfl_xor(s, o);
  if ((tid&63)==0) red[tid>>6] = s;
  __syncthreads();
  if (tid==0) atomicAdd(pen, (red[0]+red[1]+red[2]+red[3]) * (1.0f/64.0f));
}

// ---------------- M = einsum('brt,bth->brh', A, Hout), bf16 out ----------------
__global__ __launch_bounds__(256)
void attnM_kernel(const float* __restrict__ A, const u16* __restrict__ Hout,
                  u16* __restrict__ Mout)
{
  __shared__ __align__(16) float Af[RR*TT];
  int b = blockIdx.x >> 2;
  int ch = blockIdx.x & 3;
  int tid = threadIdx.x;
  for (int i=tid;i<RR*TT;i+=256) Af[i] = A[(size_t)b*RR*TT + i];
  __syncthreads();
  int h = ch*256 + tid;
  float m[RR];
  #pragma unroll
  for (int r=0;r<RR;r++) m[r] = 0.f;
  for (int t=0;t<TT;t+=4){
    float hv0 = b2f(Hout[((size_t)b*TT + t+0)*H2 + h]);
    float hv1 = b2f(Hout[((size_t)b*TT + t+1)*H2 + h]);
    float hv2 = b2f(Hout[((size_t)b*TT + t+2)*H2 + h]);
    float hv3 = b2f(Hout[((size_t)b*TT + t+3)*H2 + h]);
    #pragma unroll
    for (int r=0;r<RR;r++){
      f32x4 a4 = *(const f32x4*)&Af[r*TT + t];
      m[r] += a4.x*hv0 + a4.y*hv1 + a4.z*hv2 + a4.w*hv3;
    }
  }
  #pragma unroll
  for (int r=0;r<RR;r++) Mout[((size_t)b*RR + r)*H2 + h] = f2b(m[r]);
}

// ---------------- R1 += BM @ Wm^T partials (K-split x8); relu+bias in dec ----------------
__global__ __launch_bounds__(256)
void mlp1_kernel(const u16* __restrict__ BM, const float* __restrict__ Wm,
                 float* __restrict__ R1)
{
  int kc = blockIdx.x >> 5;                 // 0..7 K-chunk
  int xb = blockIdx.x & 31;
  int w = xb*4 + (threadIdx.x>>6);
  if (w >= MLPH/16) return;                 // 125 waves per K-chunk
  int lane = threadIdx.x & 63;
  int q = lane>>4, ln = lane&15;
  f32x4 z4 = {0.f,0.f,0.f,0.f};
  f32x4 acc[4] = {z4,z4,z4,z4};
  const float* wrow = Wm + (size_t)(w*16 + ln)*KMLP;
  for (int ks = kc*KCH; ks < (kc+1)*KCH; ks += 32){
    s8v bf = cvt8t(&wrow[ks + q*8]);
    #pragma unroll
    for (int i=0;i<4;i++){
      s8v af = *(const s8v*)&BM[(size_t)(i*16+ln)*KMLP + ks + q*8];
      acc[i] = __builtin_amdgcn_mfma_f32_16x16x32_bf16(af, bf, acc[i], 0,0,0);
    }
  }
  int n = w*16 + ln;
  #pragma unroll
  for (int i=0;i<4;i++){
    #pragma unroll
    for (int r=0;r<4;r++){
      int m = i*16 + q*4 + r;
      atomicAdd(&R1[(size_t)m*MLPH + n], acc[i][r]);
    }
  }
}

// ---------------- decoded = relu(R1+bm) @ Wd^T + bd, wave per output ----------------
__global__ __launch_bounds__(256)
void dec_kernel(const float* __restrict__ R1, const float* __restrict__ bm,
                const float* __restrict__ Wd, const float* __restrict__ bd,
                float* __restrict__ dec)
{
  int w = blockIdx.x*4 + (threadIdx.x>>6);   // 0..319
  int lane = threadIdx.x & 63;
  int m = w/5, n = w%5;
  float s = 0.f;
  for (int k=lane;k<MLPH;k+=64){
    float v = R1[(size_t)m*MLPH+k] + bm[k];
    s += fmaxf(v, 0.f)*Wd[(size_t)n*MLPH+k];
  }
  #pragma unroll
  for (int o=1;o<64;o<<=1) s += __shfl_xor(s, o);
  if (lane==0) dec[m*5+n] = s + bd[n];
}

__global__ __launch_bounds__(384)
void fin_kernel(const float* __restrict__ dec, const float* __restrict__ pen,
                float* __restrict__ out)
{
  int i = threadIdx.x;
  if (i < 320) out[i] = dec[i];
  if (i == 320) out[320] = *pen;
}

__global__ void zero_out_kernel(float* out){ int i = blockIdx.x*256 + threadIdx.x; if (i < 321) out[i] = 0.f; }

extern "C" void kernel_launch(void* const* d_in, const int* in_sizes, int n_in,
                              void* d_out, int out_size, void* d_ws, size_t ws_size,
                              hipStream_t stream)
{
  const int*   ids  = (const int*)d_in[0];
  const int*   lens = (const int*)d_in[1];
  const float* emb  = (const float*)d_in[2];
  const float* Wihf = (const float*)d_in[3];
  const float* Whhf = (const float*)d_in[4];
  const float* Wihb = (const float*)d_in[5];
  const float* Whhb = (const float*)d_in[6];
  const float* W1   = (const float*)d_in[7];
  const float* W2   = (const float*)d_in[8];
  const float* Wm   = (const float*)d_in[9];
  const float* bm   = (const float*)d_in[10];
  const float* Wd   = (const float*)d_in[11];
  const float* bd   = (const float*)d_in[12];

  char* ws = (char*)d_ws;
  size_t off = 0;
  auto nxt = [&](size_t sz){ size_t r = off; off += (sz + 255) & ~(size_t)255; return r; };
  const size_t HRsz = (size_t)2*32*4*512*4*32*4;   // 67,108,864 B
  size_t oZ   = nxt(4096);
  size_t oXf  = nxt((size_t)MROWS*KX*2);
  size_t oHout= nxt((size_t)BT*TT*H2*2);
  size_t oW1p = nxt((size_t)DAP*H2*2);
  size_t oW2p = nxt((size_t)RP*DAP*2);
  size_t oHb  = nxt((size_t)2*2*BT*HH*2);
  // HR aliases the phase-2 buffers (s1/s2/A/M/R1/dec): HR is dead after repack,
  // phase-2 buffers are written only after repack.
  size_t oBig = nxt(HRsz);
  size_t p2 = oBig;
  auto sub = [&](size_t sz){ size_t r = p2; p2 += (sz + 255) & ~(size_t)255; return r; };
  size_t oS1  = sub((size_t)MROWS*DAP*2);
  size_t oS2  = sub((size_t)MROWS*RP*2);
  size_t oA   = sub((size_t)BT*RR*TT*4);
  size_t oM   = sub((size_t)BT*RR*H2*2);
  size_t oR1  = sub((size_t)BT*MLPH*4);
  size_t oDec = sub(2048);
  size_t need = off;          // phase-2 total (41.9MB) < HRsz, stays inside oBig

  if (ws_size < need) {           // fail loudly (deterministic zeros), no OOB writes
    zero_out_kernel<<<2, 256, 0, stream>>>((float*)d_out);
    return;
  }

  u16* Xf    = (u16*)(ws + oXf);
  u16* Hout  = (u16*)(ws + oHout);
  u16* W1p   = (u16*)(ws + oW1p);
  u16* W2p   = (u16*)(ws + oW2p);
  u16* hb    = (u16*)(ws + oHb);
  unsigned* HR = (unsigned*)(ws + oBig);
  u16* s1    = (u16*)(ws + oS1);
  u16* s2    = (u16*)(ws + oS2);
  float* Ab  = (float*)(ws + oA);
  u16* Mo    = (u16*)(ws + oM);
  float* R1  = (float*)(ws + oR1);
  float* dec = (float*)(ws + oDec);
  unsigned* flags = (unsigned*)(ws + oZ);
  float* pen = (float*)(ws + oZ + 2048);

  hipMemsetAsync(ws + oZ, 0, 4096, stream);            // flags + penal accumulator

  embed_kernel<<<8192, 256, 0, stream>>>(ids, lens, emb, Xf);
  padcvt_kernel<<<(DAP*H2+255)/256, 256, 0, stream>>>(W1, W1p, 350, H2, DAP, H2);
  padcvt_kernel<<<(RP*DAP+255)/256, 256, 0, stream>>>(W2, W2p, RR, 350, RP, DAP);

  lstm_kernel<<<64, 256, 0, stream>>>(Wihf, Whhf, Wihb, Whhb, Xf, lens, hb, HR, flags);

  repack_kernel<<<16384, 256, 0, stream>>>(HR, lens, Hout);

  // R1 zero AFTER repack is enqueued (R1 aliases HR region; memset here is
  // stream-ordered after repack completes reading HR)
  hipMemsetAsync(ws + oR1, 0, (size_t)BT*MLPH*4, stream);

  dim3 gS1(DAP/128, MROWS/128);
  gemm_bt<1><<<gS1, 256, 0, stream>>>(Hout, W1p, s1, MROWS, DAP, H2);
  dim3 gS2(RP/128, MROWS/128);
  gemm_bt<0><<<gS2, 256, 0, stream>>>(s1, W2p, s2, MROWS, RP, DAP);

  softmax_kernel<<<480, 256, 0, stream>>>(s2, lens, Ab);
  penal_kernel<<<64, 256, 0, stream>>>(Ab, pen);
  attnM_kernel<<<256, 256, 0, stream>>>(Ab, Hout, Mo);
  mlp1_kernel<<<256, 256, 0, stream>>>(Mo, Wm, R1);
  dec_kernel<<<80, 256, 0, stream>>>(R1, bm, Wd, bd, dec);
  fin_kernel<<<1, 384, 0, stream>>>(dec, pen, (float*)d_out);
  (void)in_sizes; (void)n_in; (void)out_size; (void)ws_size;
}

// Round 7
// 3221.210 us; speedup vs baseline: 1.2253x; 1.0419x over previous
//
#include <hip/hip_runtime.h>
#include <stdint.h>

typedef unsigned short u16;
typedef unsigned long long u64;
typedef short s8v __attribute__((ext_vector_type(8)));
typedef float f32x4 __attribute__((ext_vector_type(4)));

#define BT    64
#define TT    512
#define NINP  300
#define KX    320
#define HH    512
#define DAP   384
#define RR    30
#define RP    128
#define MROWS 32768
#define MLPH  2000
#define H2    1024
#define KSPL  8
#define KMLP  30720
#define KCH   (KMLP/KSPL)   // 3840

__device__ inline float b2f(u16 u){ union{unsigned i; float f;} v; v.i = ((unsigned)u)<<16; return v.f; }
__device__ inline u16 f2b(float x){ union{unsigned i; float f;} v; v.f = x; unsigned b = v.i;
  unsigned r = (b + 0x7fffu + ((b>>16)&1u))>>16; return (u16)r; }

// fast tanh: 1 - 2/(e^{2x}+1). Exact at +-inf, ~1e-6 rel err; bf16-safe.
__device__ inline float ftanh(float x){
  float e = __expf(2.f*x);
  return 1.f - 2.f/(e + 1.f);
}

// truncating f32x8 -> bf16x8 pack (streaming Wm)
__device__ inline s8v cvt8t(const float* p){
  union { unsigned u[4]; s8v v; } r;
  #pragma unroll
  for (int i=0;i<4;i++){
    unsigned lo = __float_as_uint(p[2*i])   >> 16;
    unsigned hi = __float_as_uint(p[2*i+1]) & 0xFFFF0000u;
    r.u[i] = lo | hi;
  }
  return r.v;
}

// ---------------- embedding gather f32->bf16 (+mask), t-major rows r = t*64+b ----------------
__global__ __launch_bounds__(256)
void embed_kernel(const int* __restrict__ ids, const int* __restrict__ lens,
                  const float* __restrict__ emb, u16* __restrict__ Xf)
{
  int w = blockIdx.x*4 + (threadIdx.x>>6);  // row 0..32767
  int lane = threadIdx.x & 63;
  int b = w & 63, t = w >> 6;
  int len = lens[b];
  int id = ids[b*TT + t];
  bool valid = t < len;
  const float* src = emb + (size_t)id*NINP;
  #pragma unroll
  for (int i=0;i<5;i++){
    int col = lane + i*64;
    float v = (valid && col < NINP) ? src[col] : 0.f;
    Xf[(size_t)w*KX + col] = f2b(v);
  }
}

// ---------------- zero-padding copy with f32->bf16 convert ----------------
__global__ void padcvt_kernel(const float* __restrict__ src, u16* __restrict__ dst,
                              int srows, int scols, int drows, int dcols)
{
  size_t i = (size_t)blockIdx.x*blockDim.x + threadIdx.x;
  size_t tot = (size_t)drows*dcols;
  if (i >= tot) return;
  int r = (int)(i / dcols), c = (int)(i % dcols);
  dst[i] = (r < srows && c < scols) ? f2b(src[(size_t)r*scols + c]) : (u16)0;
}

// ---------------- 128x128-tile bf16 MFMA GEMM: C = act(A[M,K] * B[N,K]^T) ----------------
template<int ACT>
__global__ __launch_bounds__(256)
void gemm_bt(const u16* __restrict__ A, const u16* __restrict__ Bm, u16* __restrict__ C,
             int M, int N, int K)
{
  __shared__ u16 As[128][40];
  __shared__ u16 Bs[128][40];
  const int bn0 = blockIdx.x * 128;
  const int bm0 = blockIdx.y * 128;
  const int tid = threadIdx.x;
  const int wid = tid >> 6, lane = tid & 63;
  const int q = lane >> 4, ln = lane & 15;
  const int moff = (wid >> 1) * 64, noff = (wid & 1) * 64;
  f32x4 acc[4][4];
  f32x4 z4 = {0.f,0.f,0.f,0.f};
  #pragma unroll
  for (int i=0;i<4;i++){ acc[i][0]=z4; acc[i][1]=z4; acc[i][2]=z4; acc[i][3]=z4; }

  const int c0 = tid*2;
  const int r0 = c0>>2, kc0 = (c0&3)*8;
  const int c1 = c0+1;
  const int r1 = c1>>2, kc1 = (c1&3)*8;

  for (int kk = 0; kk < K; kk += 32) {
    *(uint4*)&As[r0][kc0] = *(const uint4*)&A[(size_t)(bm0+r0)*K + kk + kc0];
    *(uint4*)&As[r1][kc1] = *(const uint4*)&A[(size_t)(bm0+r1)*K + kk + kc1];
    *(uint4*)&Bs[r0][kc0] = *(const uint4*)&Bm[(size_t)(bn0+r0)*K + kk + kc0];
    *(uint4*)&Bs[r1][kc1] = *(const uint4*)&Bm[(size_t)(bn0+r1)*K + kk + kc1];
    __syncthreads();
    s8v af[4], bf[4];
    #pragma unroll
    for (int i=0;i<4;i++) af[i] = *(const s8v*)&As[moff + 16*i + ln][q*8];
    #pragma unroll
    for (int j=0;j<4;j++) bf[j] = *(const s8v*)&Bs[noff + 16*j + ln][q*8];
    #pragma unroll
    for (int i=0;i<4;i++)
      #pragma unroll
      for (int j=0;j<4;j++)
        acc[i][j] = __builtin_amdgcn_mfma_f32_16x16x32_bf16(af[i], bf[j], acc[i][j], 0,0,0);
    __syncthreads();
  }
  #pragma unroll
  for (int i=0;i<4;i++){
    #pragma unroll
    for (int j=0;j<4;j++){
      #pragma unroll
      for (int r=0;r<4;r++){
        int m = bm0 + moff + 16*i + q*4 + r;
        int n = bn0 + noff + 16*j + ln;
        float v = acc[i][j][r];
        if (ACT == 1) v = ftanh(v);
        C[(size_t)m*N + n] = f2b(v);
      }
    }
  }
}

// ---------------- persistent bidirectional LSTM ----------------
// 64 blocks: [0,32) fwd, [32,64) bwd. Block owns 16 hidden units.
// R7 = R6 + MALL-resident exchange (the one change).
//  R6 evidence: WRITE_SIZE 132MB = HR(64) + h-exchange(64) -> the sc0sc1
//  h/flag stores are write-through NO-ALLOCATE: they land in HBM, the MALL
//  never holds the line. So flag-visible latency = HBM write (~1000cy), every
//  poll round = HBM fetch (the 379MB FETCH_SIZE), first h reader = HBM miss.
//  FIX: h-exchange stores and flag store become global_atomic_swap (no
//  return): atomics execute AT the coherence point and ALLOCATE there, so
//  the h/flag lines stay MALL-resident. Consumer sc0sc1 loads + relaxed
//  agent poll loads are served by MALL (~500cy) instead of HBM.
//  Ordering is unchanged and stronger: h-swaps count in vmcnt and are
//  drained (vmcnt(14)) before the barrier; flag swap issues after -> a
//  consumer observing flag>=t at MALL reads h from the same MALL.
//  All other structure identical to R6 (x cross-step prefetch in regs,
//  bw[4][16] weights in 256 regs, BxL x-weights in 40KB LDS, raw barriers,
//  per-ks vmcnt(15-ks)+sched_barrier h staging).
__global__ __launch_bounds__(256, 1)
void lstm_kernel(const float* __restrict__ Wih_f, const float* __restrict__ Whh_f,
                 const float* __restrict__ Wih_b, const float* __restrict__ Whh_b,
                 const u16* __restrict__ Xf, const int* __restrict__ lens_g,
                 u16* hbuf,                  // [2 dir][2][64][512] bf16
                 unsigned* __restrict__ HR,  // [2][32][4][512][4][32] u32 staging
                 unsigned* flags)            // [2][32] u32 (one per block)
{
  __shared__ s8v BxL[40][64];   // 40 KiB x-part B-frags: [gt*10+ks][lane]
  const int bid = blockIdx.x;
  const int dir = bid >> 5;
  const int blk = bid & 31;
  const int j0 = blk * 16;
  const int tid = threadIdx.x;
  const int wv = tid >> 6, lane = tid & 63;
  const int q = lane >> 4, ln = lane & 15;
  const float* Wih = dir ? Wih_b : Wih_f;
  const float* Whh = dir ? Whh_b : Whh_f;

  // x-part weight frags -> LDS (wave 0 builds; each lane builds its own frag)
  if (wv == 0) {
    #pragma unroll
    for (int gt=0; gt<4; gt++){
      #pragma unroll
      for (int ks=0; ks<10; ks++){
        int wrow = gt*HH + j0 + ln;
        int col0 = ks*32 + q*8;
        union { u16 h[8]; s8v v; } pk;
        #pragma unroll
        for (int e=0;e<8;e++){
          int col = col0 + e;
          pk.h[e] = (col < NINP) ? f2b(Wih[(size_t)wrow*NINP + col]) : (u16)0;
        }
        BxL[gt*10+ks][lane] = pk.v;
      }
    }
  }

  // h-part weight frags -> registers (256 VGPR): bw[gt][ks]; B n-row = gt*16+ln
  s8v bw[4][16];
  #pragma unroll
  for (int gt=0; gt<4; gt++){
    #pragma unroll
    for (int ks=0; ks<16; ks++){
      int wrow = gt*HH + j0 + ln;
      int col0 = ks*32 + q*8;
      const float4* wp = (const float4*)&Whh[(size_t)wrow*HH + col0];
      float4 a = wp[0], b = wp[1];
      union { unsigned u[4]; s8v v; } pk;
      pk.u[0] = (unsigned)f2b(a.x) | ((unsigned)f2b(a.y)<<16);
      pk.u[1] = (unsigned)f2b(a.z) | ((unsigned)f2b(a.w)<<16);
      pk.u[2] = (unsigned)f2b(b.x) | ((unsigned)f2b(b.y)<<16);
      pk.u[3] = (unsigned)f2b(b.z) | ((unsigned)f2b(b.w)<<16);
      bw[gt][ks] = pk.v;
    }
  }

  const int bat0 = wv*16;
  const int alen = lens_g[bat0 + ln];       // per-lane A-row length (bwd x rows)
  __syncthreads();   // init drain: loop entry has 0 outstanding vmem

  float c_state[4] = {0.f,0.f,0.f,0.f};
  const int j = j0 + ln;

  u16* hb = hbuf + (size_t)dir*2*BT*HH;
  unsigned* myflags = flags + dir*32;       // 128 B per dir, its own lines

  // prologue: prefetch x for t=0 (alen >= 1 guaranteed)
  s8v xv[10];
  {
    int tr = (dir == 0) ? 0 : (alen - 1);
    int xr = tr*BT + bat0 + ln;
    const u16* xp = Xf + (size_t)xr*KX + q*8;
    #pragma unroll
    for (int ks=0; ks<10; ks++)
      asm volatile("global_load_dwordx4 %0, %1, off offset:%2"
                   : "=v"(xv[ks]) : "v"(xp), "n"(ks*64) : "memory");
  }

  for (int t = 0; t < TT; t++) {
    s8v hreg[16];
    if (t > 0) {
      // ---- wave 0 polls the 32 per-block flags (2 MALL-resident lines) ----
      if (wv == 0) {
        unsigned tgt = (unsigned)t;
        int guard = 0;
        for (;;) {
          unsigned v = (lane < 32)
            ? __hip_atomic_load(&myflags[lane], __ATOMIC_RELAXED, __HIP_MEMORY_SCOPE_AGENT)
            : tgt;
          if (__ballot(v >= tgt) == ~0ull) break;
          __builtin_amdgcn_s_sleep(1);
          if (++guard > (1<<20)) break;     // deadlock escape, never expected
        }
      }
      __builtin_amdgcn_s_barrier();
    }

    // h loads (bypass L1/L2, served by MALL which holds the atomic-written h)
    {
      const u16* hp = hb + (size_t)(t & 1)*BT*HH + (size_t)(bat0 + ln)*HH + q*8;
      #pragma unroll
      for (int ks = 0; ks < 16; ks++)
        asm volatile("global_load_dwordx4 %0, %1, off offset:%2 sc0 sc1"
                     : "=v"(hreg[ks]) : "v"(hp), "n"(ks*64) : "memory");
    }

    // wall: leave exactly the 16 h-loads outstanding (drains prev-tail HR+x;
    // those completed during the tail/poll window -> near-free)
    asm volatile("s_waitcnt vmcnt(16)" ::: "memory");
    __builtin_amdgcn_sched_barrier(0);

    f32x4 acc[4];
    f32x4 z4 = {0.f,0.f,0.f,0.f};
    #pragma unroll
    for (int gt=0; gt<4; gt++) acc[gt] = z4;

    // x-part: xv already in regs; compiler pipelines BxL ds_reads + 40 MFMAs
    #pragma unroll
    for (int ks=0; ks<10; ks++){
      #pragma unroll
      for (int gt=0; gt<4; gt++){
        s8v bxf = BxL[gt*10+ks][lane];
        acc[gt] = __builtin_amdgcn_mfma_f32_16x16x32_bf16(xv[ks], bxf, acc[gt], 0,0,0);
      }
    }
    // h-part: PURE REGISTER MFMAs (bw resident), per-ks exact waits
    if (t > 0) {
      #pragma unroll
      for (int ks=0; ks<16; ks++) {
        asm volatile("s_waitcnt vmcnt(%0)" :: "n"(15-ks) : "memory");
        __builtin_amdgcn_sched_barrier(0);   // rule 18
        #pragma unroll
        for (int gt=0; gt<4; gt++)
          acc[gt] = __builtin_amdgcn_mfma_f32_16x16x32_bf16(hreg[ks], bw[gt][ks], acc[gt], 0,0,0);
      }
    }

    // gates -> h
    u16 hv4[4];
    #pragma unroll
    for (int r=0;r<4;r++) {
      float iv = 1.f/(1.f + __expf(-acc[0][r]));
      float fv = 1.f/(1.f + __expf(-acc[1][r]));
      float gv = ftanh(acc[2][r]);
      float ov = 1.f/(1.f + __expf(-acc[3][r]));
      float cc = fv*c_state[r] + iv*gv;
      c_state[r] = cc;
      hv4[r] = f2b(ov*ftanh(cc));
    }
    // pair-pack (even ln lanes hold u32 covering j, j+1)
    unsigned pk4[4];
    #pragma unroll
    for (int r=0;r<4;r++) {
      unsigned lo = hv4[r];
      unsigned partner = (unsigned)__shfl((int)lo, lane ^ 1);
      pk4[r] = lo | (partner << 16);
    }
    const bool evn = ((ln & 1) == 0);

    // --- tail: h-swaps first (oldest on vmcnt), then HR, then x-prefetch ---
    // h exchange via atomic swap: executes AT the MALL and allocates there.
    if (t < TT-1 && evn) {
      u16* hnxt = hb + (size_t)((t+1)&1)*BT*HH;
      #pragma unroll
      for (int r=0;r<4;r++) {
        int bat = bat0 + q*4 + r;
        unsigned* dst = (unsigned*)(hnxt + (size_t)bat*HH + j);
        asm volatile("global_atomic_swap %0, %1, off"
                     :: "v"(dst), "v"(pk4[r]) : "memory");
      }
    }
    // HR stores: per (wv,r) one wave-instruction writes one full 128B line
    if (evn) {
      size_t base = (((size_t)(dir*32 + blk)*4 + wv)*512 + (size_t)t)*4;
      #pragma unroll
      for (int r=0;r<4;r++){
        unsigned* hrp = &HR[(base + r)*32 + q*8 + (ln>>1)];
        asm volatile("global_store_dword %0, %1, off"
                     :: "v"(hrp), "v"(pk4[r]) : "memory");
      }
    }
    // x prefetch for t+1 (cached loads; latency hides under barrier+poll)
    {
      int tn = (t < TT-1) ? (t+1) : t;
      int tr = (dir == 0) ? tn : ((tn < alen) ? (alen-1-tn) : tn);
      int xr = tr*BT + bat0 + ln;
      const u16* xp = Xf + (size_t)xr*KX + q*8;
      #pragma unroll
      for (int ks=0; ks<10; ks++)
        asm volatile("global_load_dwordx4 %0, %1, off offset:%2"
                     : "=v"(xv[ks]) : "v"(xp), "n"(ks*64) : "memory");
    }
    if (t < TT-1) {
      // drain exactly the h-swaps (t=0: also the 16 stale h-loads, 34->14)
      asm volatile("s_waitcnt vmcnt(14)" ::: "memory");
      __builtin_amdgcn_s_barrier();     // raw: HR acks + x-prefetch stay in flight
      if (tid == 0) {
        unsigned* fp = &myflags[blk];
        unsigned fv = (unsigned)(t+1);
        asm volatile("global_atomic_swap %0, %1, off"
                     :: "v"(fp), "v"(fv) : "memory");
      }
    }
  }
  // HR stores (and final x loads) must complete before endpgm: repack reads HR
  asm volatile("s_waitcnt vmcnt(0)" ::: "memory");
}

// ---------------- repack HR -> Hout [b][tp][dir*512+j] (applies bwd reversal) ----------------
__global__ __launch_bounds__(256)
void repack_kernel(const unsigned* __restrict__ HR, const int* __restrict__ lens,
                   u16* __restrict__ Hout)
{
  int w = blockIdx.x*4 + (threadIdx.x>>6);   // 0..65535 : (dir,b,t)
  int lane = threadIdx.x & 63;
  int dir = w >> 15;
  int b   = (w >> 9) & 63;
  int t   = w & 511;
  int len = lens[b];
  int tp = t;
  if (dir) tp = (t < len) ? (len - 1 - t) : t;
  int blk = lane >> 1;
  int wv = b >> 4, q = (b >> 2) & 3, r = b & 3;
  size_t src = ((((size_t)(dir*32 + blk)*4 + wv)*512 + (size_t)t)*4 + r)*32
               + q*8 + (lane & 1)*4;
  uint4 v = *(const uint4*)&HR[src];
  *(uint4*)&Hout[((size_t)b*TT + tp)*H2 + dir*HH + lane*8] = v;
}

// ---------------- masked softmax over T per (b,r) row ----------------
__global__ __launch_bounds__(256)
void softmax_kernel(const u16* __restrict__ s2, const int* __restrict__ lens,
                    float* __restrict__ A)
{
  int w = blockIdx.x*4 + (threadIdx.x>>6);   // 0..1919
  int lane = threadIdx.x & 63;
  int b = w / RR, r = w % RR;
  int len = lens[b];
  float v[8];
  float mx = -1e38f;
  #pragma unroll
  for (int i=0;i<8;i++){
    int t = lane + i*64;
    float x = b2f(s2[((size_t)b*TT + t)*RP + r]);
    v[i] = (t < len) ? x : -1e38f;
    mx = fmaxf(mx, v[i]);
  }
  #pragma unroll
  for (int o=1;o<64;o<<=1) mx = fmaxf(mx, __shfl_xor(mx, o));
  float sm = 0.f;
  #pragma unroll
  for (int i=0;i<8;i++){ v[i] = __expf(v[i]-mx); sm += v[i]; }
  #pragma unroll
  for (int o=1;o<64;o<<=1) sm += __shfl_xor(sm, o);
  float inv = 1.0f/sm;
  #pragma unroll
  for (int i=0;i<8;i++){
    int t = lane + i*64;
    A[((size_t)b*RR + r)*TT + t] = v[i]*inv;
  }
}

// ---------------- penal = mean_b ||A A^T - I||_F^2 ----------------
__global__ __launch_bounds__(256)
void penal_kernel(const float* __restrict__ A, float* __restrict__ pen)
{
  __shared__ __align__(16) float Af[RR*TT];
  __shared__ float red[4];
  int b = blockIdx.x, tid = threadIdx.x;
  for (int i=tid;i<RR*TT;i+=256) Af[i] = A[(size_t)b*RR*TT + i];
  __syncthreads();
  float s = 0.f;
  for (int p = tid; p < RR*RR; p += 256) {
    int r = p/RR, c = p%RR;
    float d = 0.f;
    for (int t=0;t<TT;t++) d += Af[r*TT+t]*Af[c*TT+t];
    d -= (r==c) ? 1.f : 0.f;
    s += d*d;
  }
  #pragma unroll
  for (int o=1;o<64;o<<=1) s += __shfl_xor(s, o);
  if ((tid&63)==0) red[tid>>6] = s;
  __syncthreads();
  if (tid==0) atomicAdd(pen, (red[0]+red[1]+red[2]+red[3]) * (1.0f/64.0f));
}

// ---------------- M = einsum('brt,bth->brh', A, Hout), bf16 out ----------------
__global__ __launch_bounds__(256)
void attnM_kernel(const float* __restrict__ A, const u16* __restrict__ Hout,
                  u16* __restrict__ Mout)
{
  __shared__ __align__(16) float Af[RR*TT];
  int b = blockIdx.x >> 2;
  int ch = blockIdx.x & 3;
  int tid = threadIdx.x;
  for (int i=tid;i<RR*TT;i+=256) Af[i] = A[(size_t)b*RR*TT + i];
  __syncthreads();
  int h = ch*256 + tid;
  float m[RR];
  #pragma unroll
  for (int r=0;r<RR;r++) m[r] = 0.f;
  for (int t=0;t<TT;t+=4){
    float hv0 = b2f(Hout[((size_t)b*TT + t+0)*H2 + h]);
    float hv1 = b2f(Hout[((size_t)b*TT + t+1)*H2 + h]);
    float hv2 = b2f(Hout[((size_t)b*TT + t+2)*H2 + h]);
    float hv3 = b2f(Hout[((size_t)b*TT + t+3)*H2 + h]);
    #pragma unroll
    for (int r=0;r<RR;r++){
      f32x4 a4 = *(const f32x4*)&Af[r*TT + t];
      m[r] += a4.x*hv0 + a4.y*hv1 + a4.z*hv2 + a4.w*hv3;
    }
  }
  #pragma unroll
  for (int r=0;r<RR;r++) Mout[((size_t)b*RR + r)*H2 + h] = f2b(m[r]);
}

// ---------------- R1 += BM @ Wm^T partials (K-split x8); relu+bias in dec ----------------
__global__ __launch_bounds__(256)
void mlp1_kernel(const u16* __restrict__ BM, const float* __restrict__ Wm,
                 float* __restrict__ R1)
{
  int kc = blockIdx.x >> 5;                 // 0..7 K-chunk
  int xb = blockIdx.x & 31;
  int w = xb*4 + (threadIdx.x>>6);
  if (w >= MLPH/16) return;                 // 125 waves per K-chunk
  int lane = threadIdx.x & 63;
  int q = lane>>4, ln = lane&15;
  f32x4 z4 = {0.f,0.f,0.f,0.f};
  f32x4 acc[4] = {z4,z4,z4,z4};
  const float* wrow = Wm + (size_t)(w*16 + ln)*KMLP;
  for (int ks = kc*KCH; ks < (kc+1)*KCH; ks += 32){
    s8v bf = cvt8t(&wrow[ks + q*8]);
    #pragma unroll
    for (int i=0;i<4;i++){
      s8v af = *(const s8v*)&BM[(size_t)(i*16+ln)*KMLP + ks + q*8];
      acc[i] = __builtin_amdgcn_mfma_f32_16x16x32_bf16(af, bf, acc[i], 0,0,0);
    }
  }
  int n = w*16 + ln;
  #pragma unroll
  for (int i=0;i<4;i++){
    #pragma unroll
    for (int r=0;r<4;r++){
      int m = i*16 + q*4 + r;
      atomicAdd(&R1[(size_t)m*MLPH + n], acc[i][r]);
    }
  }
}

// ---------------- decoded = relu(R1+bm) @ Wd^T + bd, wave per output ----------------
__global__ __launch_bounds__(256)
void dec_kernel(const float* __restrict__ R1, const float* __restrict__ bm,
                const float* __restrict__ Wd, const float* __restrict__ bd,
                float* __restrict__ dec)
{
  int w = blockIdx.x*4 + (threadIdx.x>>6);   // 0..319
  int lane = threadIdx.x & 63;
  int m = w/5, n = w%5;
  float s = 0.f;
  for (int k=lane;k<MLPH;k+=64){
    float v = R1[(size_t)m*MLPH+k] + bm[k];
    s += fmaxf(v, 0.f)*Wd[(size_t)n*MLPH+k];
  }
  #pragma unroll
  for (int o=1;o<64;o<<=1) s += __shfl_xor(s, o);
  if (lane==0) dec[m*5+n] = s + bd[n];
}

__global__ __launch_bounds__(384)
void fin_kernel(const float* __restrict__ dec, const float* __restrict__ pen,
                float* __restrict__ out)
{
  int i = threadIdx.x;
  if (i < 320) out[i] = dec[i];
  if (i == 320) out[320] = *pen;
}

__global__ void zero_out_kernel(float* out){ int i = blockIdx.x*256 + threadIdx.x; if (i < 321) out[i] = 0.f; }

extern "C" void kernel_launch(void* const* d_in, const int* in_sizes, int n_in,
                              void* d_out, int out_size, void* d_ws, size_t ws_size,
                              hipStream_t stream)
{
  const int*   ids  = (const int*)d_in[0];
  const int*   lens = (const int*)d_in[1];
  const float* emb  = (const float*)d_in[2];
  const float* Wihf = (const float*)d_in[3];
  const float* Whhf = (const float*)d_in[4];
  const float* Wihb = (const float*)d_in[5];
  const float* Whhb = (const float*)d_in[6];
  const float* W1   = (const float*)d_in[7];
  const float* W2   = (const float*)d_in[8];
  const float* Wm   = (const float*)d_in[9];
  const float* bm   = (const float*)d_in[10];
  const float* Wd   = (const float*)d_in[11];
  const float* bd   = (const float*)d_in[12];

  char* ws = (char*)d_ws;
  size_t off = 0;
  auto nxt = [&](size_t sz){ size_t r = off; off += (sz + 255) & ~(size_t)255; return r; };
  const size_t HRsz = (size_t)2*32*4*512*4*32*4;   // 67,108,864 B
  size_t oZ   = nxt(4096);
  size_t oXf  = nxt((size_t)MROWS*KX*2);
  size_t oHout= nxt((size_t)BT*TT*H2*2);
  size_t oW1p = nxt((size_t)DAP*H2*2);
  size_t oW2p = nxt((size_t)RP*DAP*2);
  size_t oHb  = nxt((size_t)2*2*BT*HH*2);
  // HR aliases the phase-2 buffers (s1/s2/A/M/R1/dec): HR is dead after repack,
  // phase-2 buffers are written only after repack.
  size_t oBig = nxt(HRsz);
  size_t p2 = oBig;
  auto sub = [&](size_t sz){ size_t r = p2; p2 += (sz + 255) & ~(size_t)255; return r; };
  size_t oS1  = sub((size_t)MROWS*DAP*2);
  size_t oS2  = sub((size_t)MROWS*RP*2);
  size_t oA   = sub((size_t)BT*RR*TT*4);
  size_t oM   = sub((size_t)BT*RR*H2*2);
  size_t oR1  = sub((size_t)BT*MLPH*4);
  size_t oDec = sub(2048);
  size_t need = off;          // phase-2 total (41.9MB) < HRsz, stays inside oBig

  if (ws_size < need) {           // fail loudly (deterministic zeros), no OOB writes
    zero_out_kernel<<<2, 256, 0, stream>>>((float*)d_out);
    return;
  }

  u16* Xf    = (u16*)(ws + oXf);
  u16* Hout  = (u16*)(ws + oHout);
  u16* W1p   = (u16*)(ws + oW1p);
  u16* W2p   = (u16*)(ws + oW2p);
  u16* hb    = (u16*)(ws + oHb);
  unsigned* HR = (unsigned*)(ws + oBig);
  u16* s1    = (u16*)(ws + oS1);
  u16* s2    = (u16*)(ws + oS2);
  float* Ab  = (float*)(ws + oA);
  u16* Mo    = (u16*)(ws + oM);
  float* R1  = (float*)(ws + oR1);
  float* dec = (float*)(ws + oDec);
  unsigned* flags = (unsigned*)(ws + oZ);
  float* pen = (float*)(ws + oZ + 2048);

  hipMemsetAsync(ws + oZ, 0, 4096, stream);            // flags + penal accumulator

  embed_kernel<<<8192, 256, 0, stream>>>(ids, lens, emb, Xf);
  padcvt_kernel<<<(DAP*H2+255)/256, 256, 0, stream>>>(W1, W1p, 350, H2, DAP, H2);
  padcvt_kernel<<<(RP*DAP+255)/256, 256, 0, stream>>>(W2, W2p, RR, 350, RP, DAP);

  lstm_kernel<<<64, 256, 0, stream>>>(Wihf, Whhf, Wihb, Whhb, Xf, lens, hb, HR, flags);

  repack_kernel<<<16384, 256, 0, stream>>>(HR, lens, Hout);

  // R1 zero AFTER repack is enqueued (R1 aliases HR region; memset here is
  // stream-ordered after repack completes reading HR)
  hipMemsetAsync(ws + oR1, 0, (size_t)BT*MLPH*4, stream);

  dim3 gS1(DAP/128, MROWS/128);
  gemm_bt<1><<<gS1, 256, 0, stream>>>(Hout, W1p, s1, MROWS, DAP, H2);
  dim3 gS2(RP/128, MROWS/128);
  gemm_bt<0><<<gS2, 256, 0, stream>>>(s1, W2p, s2, MROWS, RP, DAP);

  softmax_kernel<<<480, 256, 0, stream>>>(s2, lens, Ab);
  penal_kernel<<<64, 256, 0, stream>>>(Ab, pen);
  attnM_kernel<<<256, 256, 0, stream>>>(Ab, Hout, Mo);
  mlp1_kernel<<<256, 256, 0, stream>>>(Mo, Wm, R1);
  dec_kernel<<<80, 256, 0, stream>>>(R1, bm, Wd, bd, dec);
  fin_kernel<<<1, 384, 0, stream>>>(dec, pen, (float*)d_out);
  (void)in_sizes; (void)n_in; (void)out_size; (void)ws_size;
}